// Round 5
// baseline (509.891 us; speedup 1.0000x reference)
//
#include <hip/hip_runtime.h>
#include <hip/hip_bf16.h>

#define NH 16
#define HD 64
#define CE 1024
#define TT 2048
#define BB 2
#define MR (BB*TT)   // 4096 rows
#define SWZ(r) ((((r) & 7)) ^ (((r) >> 3) & 3))
#define LOG2E 1.44269504f

typedef __attribute__((ext_vector_type(4))) float f32x4;
typedef __attribute__((ext_vector_type(16))) float f32x16;
typedef __attribute__((ext_vector_type(8))) short s16x8;
typedef __attribute__((ext_vector_type(2))) unsigned int u32x2;
typedef unsigned int u32;
typedef unsigned short u16;

__device__ __forceinline__ void gld16(const void* g, void* l) {
  __builtin_amdgcn_global_load_lds((const __attribute__((address_space(1))) unsigned int*)g,
                                   (__attribute__((address_space(3))) unsigned int*)l, 16, 0, 0);
}
__device__ __forceinline__ u16 f2b(float f) {
  union { __hip_bfloat16 b; u16 u; } t;
  t.b = __float2bfloat16(f);
  return t.u;
}
__device__ __forceinline__ u32 pk2(float a, float b) {
  return (u32)f2b(a) | ((u32)f2b(b) << 16);
}
__device__ __forceinline__ float red64_sum(float v) {
#pragma unroll
  for (int m = 1; m < 64; m <<= 1) v += __shfl_xor(v, m, 64);
  return v;
}
__device__ __forceinline__ float softplusf(float x) {
  return x > 20.0f ? x : log1pf(expf(x));
}

// ---------------- x -> bf16 ----------------
__global__ __launch_bounds__(256) void cvt_x(const float* __restrict__ x,
                                             u16* __restrict__ xb, int n4) {
  int stride = gridDim.x * blockDim.x;
  for (int i = blockIdx.x * blockDim.x + threadIdx.x; i < n4; i += stride) {
    float4 v = ((const float4*)x)[i];
    union { u16 u[4]; uint2 p; } o;
    o.u[0] = f2b(v.x); o.u[1] = f2b(v.y); o.u[2] = f2b(v.z); o.u[3] = f2b(v.w);
    ((uint2*)xb)[i] = o.p;
  }
}

// ------- W [K][N] fp32 -> Wt [N][K] bf16 -------
__global__ __launch_bounds__(256) void cvt_wt(const float* __restrict__ W0, const float* __restrict__ W1,
                                              const float* __restrict__ W2, const float* __restrict__ W3,
                                              u16* __restrict__ T0, u16* __restrict__ T1,
                                              u16* __restrict__ T2, u16* __restrict__ T3) {
  const float* W = blockIdx.z == 0 ? W0 : blockIdx.z == 1 ? W1 : blockIdx.z == 2 ? W2 : W3;
  u16* T = blockIdx.z == 0 ? T0 : blockIdx.z == 1 ? T1 : blockIdx.z == 2 ? T2 : T3;
  __shared__ float t[64][65];
  int k0 = blockIdx.x * 64, n0 = blockIdx.y * 64;
  int row = threadIdx.x >> 2, seg = threadIdx.x & 3;
#pragma unroll
  for (int i = 0; i < 4; ++i) {
    float4 v = *(const float4*)(W + (size_t)(k0 + row) * CE + n0 + seg * 16 + i * 4);
    int c = seg * 16 + i * 4;
    t[row][c + 0] = v.x; t[row][c + 1] = v.y; t[row][c + 2] = v.z; t[row][c + 3] = v.w;
  }
  __syncthreads();
#pragma unroll
  for (int it = 0; it < 2; ++it) {
    int c = threadIdx.x + it * 256;
    int n = c >> 3, ks = (c & 7) * 8;
    union { u16 u[8]; uint4 p; } o;
#pragma unroll
    for (int e = 0; e < 8; ++e) o.u[e] = f2b(t[ks + e][n]);
    *(uint4*)(T + (size_t)(n0 + n) * CE + k0 + ks) = o.p;
  }
}

// ---------------- bf16 GEMM: C[M,N] = A[M,K] @ Bt[N,K]^T ----------------
#define BM 128
#define BN 128
#define BK 64
__global__ __launch_bounds__(256) void gemm3(const u16* __restrict__ A,
    const u16* __restrict__ B0, const u16* __restrict__ B1,
    const u16* __restrict__ B2,
    float* __restrict__ C0, float* __restrict__ C1, float* __restrict__ C2,
    int M, int N, int K) {
  const u16* Bt = blockIdx.z == 0 ? B0 : blockIdx.z == 1 ? B1 : B2;
  float* C = blockIdx.z == 0 ? C0 : blockIdx.z == 1 ? C1 : C2;
  __shared__ __align__(16) u16 aT[BM * BK];  // linear dest; source pre-swizzled
  __shared__ __align__(16) u16 bT[BN * BK];
  int tid = threadIdx.x;
  int w = tid >> 6, lane = tid & 63, q4 = lane >> 4, r16 = lane & 15;
  int m0 = blockIdx.y * BM, n0 = blockIdx.x * BN;
  int wm = (w >> 1) * 64, wn = (w & 1) * 64;
  f32x4 acc[4][4] = {};
  for (int k0 = 0; k0 < K; k0 += BK) {
#pragma unroll
    for (int it = 0; it < 4; ++it) {
      int c = tid + it * 256;
      int row = c >> 3, sl = c & 7;
      gld16(A + (size_t)(m0 + row) * K + k0 + ((sl ^ SWZ(row)) << 3), &aT[c * 8]);
      gld16(Bt + (size_t)(n0 + row) * K + k0 + ((sl ^ SWZ(row)) << 3), &bT[c * 8]);
    }
    __syncthreads();
#pragma unroll
    for (int kk = 0; kk < 2; ++kk) {
      s16x8 af[4], bfr[4];
#pragma unroll
      for (int i = 0; i < 4; ++i) {
        int ra = wm + i * 16 + r16;
        af[i] = *(const s16x8*)((char*)aT + ra * 128 + ((((kk << 2) | q4) ^ SWZ(ra)) << 4));
        int rb = wn + i * 16 + r16;
        bfr[i] = *(const s16x8*)((char*)bT + rb * 128 + ((((kk << 2) | q4) ^ SWZ(rb)) << 4));
      }
#pragma unroll
      for (int i = 0; i < 4; ++i)
#pragma unroll
        for (int j = 0; j < 4; ++j)
          acc[i][j] = __builtin_amdgcn_mfma_f32_16x16x32_bf16(af[i], bfr[j], acc[i][j], 0, 0, 0);
    }
    __syncthreads();
  }
#pragma unroll
  for (int i = 0; i < 4; ++i)
#pragma unroll
    for (int j = 0; j < 4; ++j)
#pragma unroll
      for (int r = 0; r < 4; ++r) {
        int gm = m0 + wm + i * 16 + (q4 << 2) + r;
        int gn = n0 + wn + j * 16 + r16;
        C[(size_t)gm * N + gn] = acc[i][j][r];
      }
}

// ---- RMSNorm(q,k) + gate; q/k -> [B,H,T,D] bf16 (scale*log2e folded into q),
//      v -> [B,H,D,T] bf16; cg pre-multiplied by log2e ----
__global__ __launch_bounds__(256) void rmsgate(const float* __restrict__ q, const float* __restrict__ k,
    const float* __restrict__ v, const float* __restrict__ qw, const float* __restrict__ kw,
    const float* __restrict__ omega, const float* __restrict__ u,
    u16* __restrict__ qb, u16* __restrict__ kb,
    u16* __restrict__ vtb, float* __restrict__ cg) {
  int b = blockIdx.z, h = blockIdx.y, t0 = blockIdx.x * 64;
  int tid = threadIdx.x, w = tid >> 6, lane = tid & 63;
  float uv = u[h * HD + lane];
  float us = red64_sum(uv * uv);
  float un = uv / fmaxf(sqrtf(us), 1e-6f);
  float qwl = qw[lane], kwl = kw[lane];
  float weff = softplusf(omega[h]) * exp2f(-0.5f * (float)(h + 1)) * LOG2E;
  size_t hb = ((size_t)(b * NH + h)) * TT;
#pragma unroll 4
  for (int it = 0; it < 16; ++it) {
    int t = t0 + w * 16 + it;
    size_t roff = ((size_t)(b * TT + t)) * CE + h * HD + lane;
    float qv = q[roff];
    float rq = rsqrtf(red64_sum(qv * qv) * (1.0f / 64.0f) + 1e-5f);
    qb[(hb + t) * HD + lane] = f2b(qv * rq * qwl * (0.125f * LOG2E));
    float kv = k[roff];
    float rk = rsqrtf(red64_sum(kv * kv) * (1.0f / 64.0f) + 1e-5f);
    float kn = kv * rk * kwl;
    kb[(hb + t) * HD + lane] = f2b(kn);
    float gl = red64_sum(kn * un) * 0.125f;
    if (lane == 0) cg[hb + t] = weff * softplusf(gl);
  }
  __shared__ u16 vt[64 * 65];
  int row = tid >> 2, seg = tid & 3;
#pragma unroll
  for (int i = 0; i < 4; ++i) {
    float4 vv = *(const float4*)(v + ((size_t)(b * TT + t0 + row)) * CE + h * HD + seg * 16 + i * 4);
    int d = seg * 16 + i * 4;
    vt[(d + 0) * 65 + row] = f2b(vv.x);
    vt[(d + 1) * 65 + row] = f2b(vv.y);
    vt[(d + 2) * 65 + row] = f2b(vv.z);
    vt[(d + 3) * 65 + row] = f2b(vv.w);
  }
  __syncthreads();
#pragma unroll
  for (int it = 0; it < 2; ++it) {
    int c = tid + it * 256;
    int d = c >> 3, js = (c & 7) * 8;
    union { u16 u[8]; uint4 p; } o;
#pragma unroll
    for (int e = 0; e < 8; ++e) o.u[e] = vt[d * 65 + js + e];
    *(uint4*)(vtb + (((size_t)(b * NH + h)) * HD + d) * TT + t0 + js) = o.p;
  }
}

// ------------- causal flash attention: split-KV x2, 2 waves/block -------------
// Each wave: swapped QK^T (32x32 MFMA), in-lane softmax, P in-register.
// Wave w handles KV tiles jt = w, w+2, ... ; merge (m,l,O) via LDS at end.
#define KVB 64
__global__ __launch_bounds__(128, 4) void attn(const u16* __restrict__ qb,
    const u16* __restrict__ kb, const u16* __restrict__ vtb,
    const float* __restrict__ cg, u16* __restrict__ y) {
  int b = blockIdx.z, h = blockIdx.y;
  int qt = gridDim.x - 1 - blockIdx.x;          // heavy tiles dispatch first
  int tid = threadIdx.x;
  int w = tid >> 6;                             // KV-split index (0/1)
  int lane = tid & 63;
  int hi = lane >> 5, q5 = lane & 31;
  __shared__ __align__(16) u16 ol[32 * 64];     // 4KB epilogue transpose
  __shared__ float mO[32][64];                  // 8KB wave1 accO
  __shared__ float mML[2][64];                  // wave1 m,l
  size_t hb = ((size_t)(b * NH + h)) * TT;
  size_t vbase = ((size_t)(b * NH + h)) * HD;
  int qrow = qt * 32 + q5;
  const u16* qptr = qb + (hb + qrow) * HD;
  s16x8 qf[4];
#pragma unroll
  for (int kc = 0; kc < 4; ++kc)
    qf[kc] = *(const s16x8*)(qptr + kc * 16 + hi * 8);
  f32x16 accO[2] = {};   // O^T tiles (d 0..31 / 32..63) x q
  float m = -1e30f, l = 0.f;
  int nt = qt / 2 + 1;
  for (int jt = w; jt < nt; jt += 2) {
    int j0 = jt * KVB;
    // ---- issue all tile loads (K, V^T, cg) ----
    const u16* kp0 = kb + (hb + j0 + q5) * HD + hi * 8;
    const u16* kp1 = kb + (hb + j0 + 32 + q5) * HD + hi * 8;
    s16x8 kf0[4], kf1[4];
#pragma unroll
    for (int kc = 0; kc < 4; ++kc) {
      kf0[kc] = *(const s16x8*)(kp0 + kc * 16);
      kf1[kc] = *(const s16x8*)(kp1 + kc * 16);
    }
    const u16* vp0 = vtb + (vbase + q5) * TT + j0 + hi * 8;
    const u16* vp1 = vtb + (vbase + 32 + q5) * TT + j0 + hi * 8;
    s16x8 vfr0[4], vfr1[4];
#pragma unroll
    for (int c = 0; c < 4; ++c) {
      vfr0[c] = *(const s16x8*)(vp0 + c * 16);
      vfr1[c] = *(const s16x8*)(vp1 + c * 16);
    }
    const float* cgp = cg + hb + j0 + 4 * hi;
    f32x4 cgA[4], cgB[4];
#pragma unroll
    for (int g = 0; g < 4; ++g) {
      cgA[g] = *(const f32x4*)(cgp + 8 * g);
      cgB[g] = *(const f32x4*)(cgp + 32 + 8 * g);
    }
    // ---- S^T = K Q ----
    f32x16 s0 = {}, s1 = {};
#pragma unroll
    for (int kc = 0; kc < 4; ++kc) {
      s0 = __builtin_amdgcn_mfma_f32_32x32x16_bf16(kf0[kc], qf[kc], s0, 0, 0, 0);
      s1 = __builtin_amdgcn_mfma_f32_32x32x16_bf16(kf1[kc], qf[kc], s1, 0, 0, 0);
    }
    // ---- bias (+ causal mask only on last tile) ----
    float dif0h = (float)(qrow - j0) - 4.0f * (float)hi;
    if (jt == nt - 1) {
#pragma unroll
      for (int r = 0; r < 16; ++r) {
        float cr = (float)((r & 3) + 8 * (r >> 2));
        float d0 = dif0h - cr, d1 = d0 - 32.f;
        float sv0 = s0[r] - d0 * cgA[r >> 2][r & 3];
        float sv1 = s1[r] - d1 * cgB[r >> 2][r & 3];
        s0[r] = (d0 >= 0.f) ? sv0 : -1e30f;
        s1[r] = (d1 >= 0.f) ? sv1 : -1e30f;
      }
    } else {
#pragma unroll
      for (int r = 0; r < 16; ++r) {
        float cr = (float)((r & 3) + 8 * (r >> 2));
        float d0 = dif0h - cr;
        s0[r] = s0[r] - d0 * cgA[r >> 2][r & 3];
        s1[r] = s1[r] - (d0 - 32.f) * cgB[r >> 2][r & 3];
      }
    }
    // ---- max tree + cross-half ----
    float t8[8];
#pragma unroll
    for (int i = 0; i < 8; ++i)
      t8[i] = fmaxf(fmaxf(s0[i], s0[i + 8]), fmaxf(s1[i], s1[i + 8]));
    float pmax = fmaxf(fmaxf(fmaxf(t8[0], t8[4]), fmaxf(t8[1], t8[5])),
                       fmaxf(fmaxf(t8[2], t8[6]), fmaxf(t8[3], t8[7])));
    pmax = fmaxf(pmax, __shfl_xor(pmax, 32, 64));
    // ---- defer-max: rescale only when max grew materially (THR = 8*log2e) ----
    if (!__all(pmax - m <= 11.54f)) {
      float mn = fmaxf(m, pmax);
      float al = exp2f(m - mn);
      m = mn;
      l *= al;
#pragma unroll
      for (int r = 0; r < 16; ++r) { accO[0][r] *= al; accO[1][r] *= al; }
    }
    // ---- exp2 + sum tree ----
#pragma unroll
    for (int r = 0; r < 16; ++r) {
      s0[r] = exp2f(s0[r] - m);
      s1[r] = exp2f(s1[r] - m);
    }
    float e8[8];
#pragma unroll
    for (int i = 0; i < 8; ++i)
      e8[i] = (s0[i] + s0[i + 8]) + (s1[i] + s1[i + 8]);
    float ps = ((e8[0] + e8[4]) + (e8[1] + e8[5])) + ((e8[2] + e8[6]) + (e8[3] + e8[7]));
    ps += __shfl_xor(ps, 32, 64);
    l += ps;
    // ---- P^T -> bf16 B-frags (permlane32_swap) + PV: O^T += V^T P^T ----
    auto pvchunk = [&](const f32x16& sc, const s16x8& v00, const s16x8& v01,
                       const s16x8& v10, const s16x8& v11) {
      u32 c01 = pk2(sc[0], sc[1]),  c23 = pk2(sc[2], sc[3]);
      u32 c45 = pk2(sc[4], sc[5]),  c67 = pk2(sc[6], sc[7]);
      u32 c89 = pk2(sc[8], sc[9]),  cAB = pk2(sc[10], sc[11]);
      u32 cCD = pk2(sc[12], sc[13]), cEF = pk2(sc[14], sc[15]);
      union { u32 wd[4]; s16x8 v; } Bf0, Bf1;
#if __has_builtin(__builtin_amdgcn_permlane32_swap)
      u32x2 sA = __builtin_amdgcn_permlane32_swap(c01, c45, false, false);
      u32x2 sB = __builtin_amdgcn_permlane32_swap(c23, c67, false, false);
      u32x2 sC = __builtin_amdgcn_permlane32_swap(c89, cCD, false, false);
      u32x2 sD = __builtin_amdgcn_permlane32_swap(cAB, cEF, false, false);
      Bf0.wd[0] = sA.x; Bf0.wd[1] = sB.x; Bf0.wd[2] = sA.y; Bf0.wd[3] = sB.y;
      Bf1.wd[0] = sC.x; Bf1.wd[1] = sD.x; Bf1.wd[2] = sC.y; Bf1.wd[3] = sD.y;
#else
      u32 x01 = (u32)__shfl_xor((int)c01, 32, 64), x23 = (u32)__shfl_xor((int)c23, 32, 64);
      u32 x45 = (u32)__shfl_xor((int)c45, 32, 64), x67 = (u32)__shfl_xor((int)c67, 32, 64);
      u32 x89 = (u32)__shfl_xor((int)c89, 32, 64), xAB = (u32)__shfl_xor((int)cAB, 32, 64);
      u32 xCD = (u32)__shfl_xor((int)cCD, 32, 64), xEF = (u32)__shfl_xor((int)cEF, 32, 64);
      Bf0.wd[0] = hi ? x45 : c01; Bf0.wd[1] = hi ? x67 : c23;
      Bf0.wd[2] = hi ? c45 : x01; Bf0.wd[3] = hi ? c67 : x23;
      Bf1.wd[0] = hi ? xCD : c89; Bf1.wd[1] = hi ? xEF : cAB;
      Bf1.wd[2] = hi ? cCD : x89; Bf1.wd[3] = hi ? cEF : xAB;
#endif
      accO[0] = __builtin_amdgcn_mfma_f32_32x32x16_bf16(v00, Bf0.v, accO[0], 0, 0, 0);
      accO[0] = __builtin_amdgcn_mfma_f32_32x32x16_bf16(v01, Bf1.v, accO[0], 0, 0, 0);
      accO[1] = __builtin_amdgcn_mfma_f32_32x32x16_bf16(v10, Bf0.v, accO[1], 0, 0, 0);
      accO[1] = __builtin_amdgcn_mfma_f32_32x32x16_bf16(v11, Bf1.v, accO[1], 0, 0, 0);
    };
    pvchunk(s0, vfr0[0], vfr0[1], vfr1[0], vfr1[1]);
    pvchunk(s1, vfr0[2], vfr0[3], vfr1[2], vfr1[3]);
  }
  // ---- merge the two KV-splits via LDS ----
  if (w == 1) {
#pragma unroll
    for (int r = 0; r < 16; ++r) {
      mO[r][lane] = accO[0][r];
      mO[16 + r][lane] = accO[1][r];
    }
    mML[0][lane] = m;
    mML[1][lane] = l;
  }
  __syncthreads();
  if (w == 1) return;
  float m1 = mML[0][lane], l1 = mML[1][lane];
  float ms = fmaxf(m, m1);
  float a0 = exp2f(m - ms), a1 = exp2f(m1 - ms);
  float lt = l * a0 + l1 * a1;
  float inv0 = a0 / lt, inv1 = a1 / lt;
  // ---- epilogue: merged O^T -> LDS transpose -> coalesced bf16 stores (wave0) ----
#pragma unroll
  for (int dt = 0; dt < 2; ++dt)
#pragma unroll
    for (int r = 0; r < 16; ++r) {
      float val = accO[dt][r] * inv0 + mO[dt * 16 + r][lane] * inv1;
      int d = 32 * dt + (r & 3) + 8 * (r >> 2) + 4 * hi;
      *(u16*)((char*)ol + q5 * 128 + (((d >> 3) ^ SWZ(q5)) << 4) + ((d & 7) << 1)) = f2b(val);
    }
  // same-wave LDS write->read; compiler inserts lgkm waits (no barrier: wave1 exited)
  int row = lane >> 1, half = lane & 1;
#pragma unroll
  for (int s4 = 0; s4 < 4; ++s4) {
    int slot = half * 4 + s4;
    s16x8 vv = *(const s16x8*)((char*)ol + row * 128 + ((slot ^ SWZ(row)) << 4));
    *(s16x8*)(y + ((size_t)(b * TT) + qt * 32 + row) * CE + h * HD + half * 32 + s4 * 8) = vv;
  }
}

extern "C" void kernel_launch(void* const* d_in, const int* in_sizes, int n_in,
                              void* d_out, int out_size, void* d_ws, size_t ws_size,
                              hipStream_t stream) {
  const float* x  = (const float*)d_in[0];
  const float* Wq = (const float*)d_in[1];
  const float* Wk = (const float*)d_in[2];
  const float* Wv = (const float*)d_in[3];
  const float* Wp = (const float*)d_in[4];
  const float* qw = (const float*)d_in[5];
  const float* kw = (const float*)d_in[6];
  const float* om = (const float*)d_in[7];
  const float* u  = (const float*)d_in[8];
  float* out = (float*)d_out;
  char* ws = (char*)d_ws;
  const size_t MB = 1024 * 1024;
  u16* xb  = (u16*)(ws + 0);
  u16* wqt = (u16*)(ws + 8 * MB);
  u16* wkt = (u16*)(ws + 10 * MB);
  u16* wvt = (u16*)(ws + 12 * MB);
  u16* wpt = (u16*)(ws + 14 * MB);
  float* qf = (float*)(ws + 16 * MB);
  float* kf = (float*)(ws + 32 * MB);
  float* vf = (float*)(ws + 48 * MB);
  u16* qbb = (u16*)(ws + 64 * MB);
  u16* kbb = (u16*)(ws + 72 * MB);
  u16* vtb = (u16*)(ws + 80 * MB);
  float* cg = (float*)(ws + 88 * MB);
  u16* yb = (u16*)(ws + 16 * MB);   // reuse qf region

  cvt_x<<<dim3(2048), dim3(256), 0, stream>>>(x, xb, MR * CE / 4);
  cvt_wt<<<dim3(16, 16, 4), dim3(256), 0, stream>>>(Wq, Wk, Wv, Wp, wqt, wkt, wvt, wpt);
  gemm3<<<dim3(8, 32, 3), dim3(256), 0, stream>>>(xb, wqt, wkt, wvt, qf, kf, vf, MR, CE, CE);
  rmsgate<<<dim3(32, 16, 2), dim3(256), 0, stream>>>(qf, kf, vf, qw, kw, om, u, qbb, kbb, vtb, cg);
  attn<<<dim3(64, 16, 2), dim3(128), 0, stream>>>(qbb, kbb, vtb, cg, yb);
  gemm3<<<dim3(8, 32, 1), dim3(256), 0, stream>>>(yb, wpt, wpt, wpt, out, out, out, MR, CE, CE);
}

// Round 7
// 320.719 us; speedup vs baseline: 1.5898x; 1.5898x over previous
//
#include <hip/hip_runtime.h>
#include <hip/hip_bf16.h>

#define NH 16
#define HD 64
#define CE 1024
#define TT 2048
#define BB 2
#define MR (BB*TT)   // 4096 rows
#define SWZ(r) ((((r) & 7)) ^ (((r) >> 3) & 3))
#define LOG2E 1.44269504f

typedef __attribute__((ext_vector_type(4))) float f32x4;
typedef __attribute__((ext_vector_type(16))) float f32x16;
typedef __attribute__((ext_vector_type(8))) short s16x8;
typedef __attribute__((ext_vector_type(2))) unsigned int u32x2;
typedef unsigned int u32;
typedef unsigned short u16;

__device__ __forceinline__ void gld16(const void* g, void* l) {
  __builtin_amdgcn_global_load_lds((const __attribute__((address_space(1))) unsigned int*)g,
                                   (__attribute__((address_space(3))) unsigned int*)l, 16, 0, 0);
}
__device__ __forceinline__ u16 f2b(float f) {
  union { __hip_bfloat16 b; u16 u; } t;
  t.b = __float2bfloat16(f);
  return t.u;
}
__device__ __forceinline__ u32 pk2(float a, float b) {
  return (u32)f2b(a) | ((u32)f2b(b) << 16);
}
__device__ __forceinline__ float red64_sum(float v) {
#pragma unroll
  for (int m = 1; m < 64; m <<= 1) v += __shfl_xor(v, m, 64);
  return v;
}
__device__ __forceinline__ float softplusf(float x) {
  return x > 20.0f ? x : log1pf(expf(x));
}

// ---------------- x -> bf16 ----------------
__global__ __launch_bounds__(256) void cvt_x(const float* __restrict__ x,
                                             u16* __restrict__ xb, int n4) {
  int stride = gridDim.x * blockDim.x;
  for (int i = blockIdx.x * blockDim.x + threadIdx.x; i < n4; i += stride) {
    float4 v = ((const float4*)x)[i];
    union { u16 u[4]; uint2 p; } o;
    o.u[0] = f2b(v.x); o.u[1] = f2b(v.y); o.u[2] = f2b(v.z); o.u[3] = f2b(v.w);
    ((uint2*)xb)[i] = o.p;
  }
}

// ------- W [K][N] fp32 -> Wt [N][K] bf16 -------
__global__ __launch_bounds__(256) void cvt_wt(const float* __restrict__ W0, const float* __restrict__ W1,
                                              const float* __restrict__ W2, const float* __restrict__ W3,
                                              u16* __restrict__ T0, u16* __restrict__ T1,
                                              u16* __restrict__ T2, u16* __restrict__ T3) {
  const float* W = blockIdx.z == 0 ? W0 : blockIdx.z == 1 ? W1 : blockIdx.z == 2 ? W2 : W3;
  u16* T = blockIdx.z == 0 ? T0 : blockIdx.z == 1 ? T1 : blockIdx.z == 2 ? T2 : T3;
  __shared__ float t[64][65];
  int k0 = blockIdx.x * 64, n0 = blockIdx.y * 64;
  int row = threadIdx.x >> 2, seg = threadIdx.x & 3;
#pragma unroll
  for (int i = 0; i < 4; ++i) {
    float4 v = *(const float4*)(W + (size_t)(k0 + row) * CE + n0 + seg * 16 + i * 4);
    int c = seg * 16 + i * 4;
    t[row][c + 0] = v.x; t[row][c + 1] = v.y; t[row][c + 2] = v.z; t[row][c + 3] = v.w;
  }
  __syncthreads();
#pragma unroll
  for (int it = 0; it < 2; ++it) {
    int c = threadIdx.x + it * 256;
    int n = c >> 3, ks = (c & 7) * 8;
    union { u16 u[8]; uint4 p; } o;
#pragma unroll
    for (int e = 0; e < 8; ++e) o.u[e] = f2b(t[ks + e][n]);
    *(uint4*)(T + (size_t)(n0 + n) * CE + k0 + ks) = o.p;
  }
}

// ---------------- bf16 GEMM: C[M,N] = A[M,K] @ Bt[N,K]^T ----------------
#define BM 128
#define BN 128
#define BK 64
__global__ __launch_bounds__(256) void gemm3(const u16* __restrict__ A,
    const u16* __restrict__ B0, const u16* __restrict__ B1,
    const u16* __restrict__ B2,
    float* __restrict__ C0, float* __restrict__ C1, float* __restrict__ C2,
    int M, int N, int K) {
  const u16* Bt = blockIdx.z == 0 ? B0 : blockIdx.z == 1 ? B1 : B2;
  float* C = blockIdx.z == 0 ? C0 : blockIdx.z == 1 ? C1 : C2;
  __shared__ __align__(16) u16 aT[BM * BK];  // linear dest; source pre-swizzled
  __shared__ __align__(16) u16 bT[BN * BK];
  int tid = threadIdx.x;
  int w = tid >> 6, lane = tid & 63, q4 = lane >> 4, r16 = lane & 15;
  int m0 = blockIdx.y * BM, n0 = blockIdx.x * BN;
  int wm = (w >> 1) * 64, wn = (w & 1) * 64;
  f32x4 acc[4][4] = {};
  for (int k0 = 0; k0 < K; k0 += BK) {
#pragma unroll
    for (int it = 0; it < 4; ++it) {
      int c = tid + it * 256;
      int row = c >> 3, sl = c & 7;
      gld16(A + (size_t)(m0 + row) * K + k0 + ((sl ^ SWZ(row)) << 3), &aT[c * 8]);
      gld16(Bt + (size_t)(n0 + row) * K + k0 + ((sl ^ SWZ(row)) << 3), &bT[c * 8]);
    }
    __syncthreads();
#pragma unroll
    for (int kk = 0; kk < 2; ++kk) {
      s16x8 af[4], bfr[4];
#pragma unroll
      for (int i = 0; i < 4; ++i) {
        int ra = wm + i * 16 + r16;
        af[i] = *(const s16x8*)((char*)aT + ra * 128 + ((((kk << 2) | q4) ^ SWZ(ra)) << 4));
        int rb = wn + i * 16 + r16;
        bfr[i] = *(const s16x8*)((char*)bT + rb * 128 + ((((kk << 2) | q4) ^ SWZ(rb)) << 4));
      }
#pragma unroll
      for (int i = 0; i < 4; ++i)
#pragma unroll
        for (int j = 0; j < 4; ++j)
          acc[i][j] = __builtin_amdgcn_mfma_f32_16x16x32_bf16(af[i], bfr[j], acc[i][j], 0, 0, 0);
    }
    __syncthreads();
  }
#pragma unroll
  for (int i = 0; i < 4; ++i)
#pragma unroll
    for (int j = 0; j < 4; ++j)
#pragma unroll
      for (int r = 0; r < 4; ++r) {
        int gm = m0 + wm + i * 16 + (q4 << 2) + r;
        int gn = n0 + wn + j * 16 + r16;
        C[(size_t)gm * N + gn] = acc[i][j][r];
      }
}

// ---- RMSNorm(q,k) + gate; q/k -> [B,H,T,D] bf16 (scale*log2e folded into q),
//      v -> [B,H,D,T] bf16; cg pre-multiplied by log2e ----
__global__ __launch_bounds__(256) void rmsgate(const float* __restrict__ q, const float* __restrict__ k,
    const float* __restrict__ v, const float* __restrict__ qw, const float* __restrict__ kw,
    const float* __restrict__ omega, const float* __restrict__ u,
    u16* __restrict__ qb, u16* __restrict__ kb,
    u16* __restrict__ vtb, float* __restrict__ cg) {
  int b = blockIdx.z, h = blockIdx.y, t0 = blockIdx.x * 64;
  int tid = threadIdx.x, w = tid >> 6, lane = tid & 63;
  float uv = u[h * HD + lane];
  float us = red64_sum(uv * uv);
  float un = uv / fmaxf(sqrtf(us), 1e-6f);
  float qwl = qw[lane], kwl = kw[lane];
  float weff = softplusf(omega[h]) * exp2f(-0.5f * (float)(h + 1)) * LOG2E;
  size_t hb = ((size_t)(b * NH + h)) * TT;
#pragma unroll 4
  for (int it = 0; it < 16; ++it) {
    int t = t0 + w * 16 + it;
    size_t roff = ((size_t)(b * TT + t)) * CE + h * HD + lane;
    float qv = q[roff];
    float rq = rsqrtf(red64_sum(qv * qv) * (1.0f / 64.0f) + 1e-5f);
    qb[(hb + t) * HD + lane] = f2b(qv * rq * qwl * (0.125f * LOG2E));
    float kv = k[roff];
    float rk = rsqrtf(red64_sum(kv * kv) * (1.0f / 64.0f) + 1e-5f);
    float kn = kv * rk * kwl;
    kb[(hb + t) * HD + lane] = f2b(kn);
    float gl = red64_sum(kn * un) * 0.125f;
    if (lane == 0) cg[hb + t] = weff * softplusf(gl);
  }
  __shared__ u16 vt[64 * 65];
  int row = tid >> 2, seg = tid & 3;
#pragma unroll
  for (int i = 0; i < 4; ++i) {
    float4 vv = *(const float4*)(v + ((size_t)(b * TT + t0 + row)) * CE + h * HD + seg * 16 + i * 4);
    int d = seg * 16 + i * 4;
    vt[(d + 0) * 65 + row] = f2b(vv.x);
    vt[(d + 1) * 65 + row] = f2b(vv.y);
    vt[(d + 2) * 65 + row] = f2b(vv.z);
    vt[(d + 3) * 65 + row] = f2b(vv.w);
  }
  __syncthreads();
#pragma unroll
  for (int it = 0; it < 2; ++it) {
    int c = tid + it * 256;
    int d = c >> 3, js = (c & 7) * 8;
    union { u16 u[8]; uint4 p; } o;
#pragma unroll
    for (int e = 0; e < 8; ++e) o.u[e] = vt[d * 65 + js + e];
    *(uint4*)(vtb + (((size_t)(b * NH + h)) * HD + d) * TT + t0 + js) = o.p;
  }
}

// ------------- causal flash attention: split-KV x2, 2 waves/block -------------
// NOTE: __launch_bounds__(128) with NO min-waves arg — round 5's (128,4) capped
// the allocator at 64 VGPR and spilled accO to scratch (WRITE_SIZE 8->403MB).
// K regs die before V regs go live (V loads issued after QK^T, hidden by softmax).
#define KVB 64
__global__ __launch_bounds__(128) void attn(const u16* __restrict__ qb,
    const u16* __restrict__ kb, const u16* __restrict__ vtb,
    const float* __restrict__ cg, u16* __restrict__ y) {
  int b = blockIdx.z, h = blockIdx.y;
  int qt = gridDim.x - 1 - blockIdx.x;          // heavy tiles dispatch first
  int tid = threadIdx.x;
  int w = tid >> 6;                             // KV-split index (0/1)
  int lane = tid & 63;
  int hi = lane >> 5, q5 = lane & 31;
  __shared__ __align__(16) u16 ol[32 * 64];     // 4KB epilogue transpose
  __shared__ float mO[32][64];                  // 8KB wave1 accO
  __shared__ float mML[2][64];                  // wave1 m,l
  size_t hb = ((size_t)(b * NH + h)) * TT;
  size_t vbase = ((size_t)(b * NH + h)) * HD;
  int qrow = qt * 32 + q5;
  const u16* qptr = qb + (hb + qrow) * HD;
  s16x8 qf[4];
#pragma unroll
  for (int kc = 0; kc < 4; ++kc)
    qf[kc] = *(const s16x8*)(qptr + kc * 16 + hi * 8);
  f32x16 accO[2] = {};   // O^T tiles (d 0..31 / 32..63) x q
  float m = -1e30f, l = 0.f;
  int nt = qt / 2 + 1;
  for (int jt = w; jt < nt; jt += 2) {
    int j0 = jt * KVB;
    // ---- K + cg loads ----
    const u16* kp0 = kb + (hb + j0 + q5) * HD + hi * 8;
    const u16* kp1 = kb + (hb + j0 + 32 + q5) * HD + hi * 8;
    s16x8 kf0[4], kf1[4];
#pragma unroll
    for (int kc = 0; kc < 4; ++kc) {
      kf0[kc] = *(const s16x8*)(kp0 + kc * 16);
      kf1[kc] = *(const s16x8*)(kp1 + kc * 16);
    }
    const float* cgp = cg + hb + j0 + 4 * hi;
    f32x4 cgA[4], cgB[4];
#pragma unroll
    for (int g = 0; g < 4; ++g) {
      cgA[g] = *(const f32x4*)(cgp + 8 * g);
      cgB[g] = *(const f32x4*)(cgp + 32 + 8 * g);
    }
    // ---- S^T = K Q ----
    f32x16 s0 = {}, s1 = {};
#pragma unroll
    for (int kc = 0; kc < 4; ++kc) {
      s0 = __builtin_amdgcn_mfma_f32_32x32x16_bf16(kf0[kc], qf[kc], s0, 0, 0, 0);
      s1 = __builtin_amdgcn_mfma_f32_32x32x16_bf16(kf1[kc], qf[kc], s1, 0, 0, 0);
    }
    // ---- issue V loads now (K regs dead; latency hides under softmax) ----
    const u16* vp0 = vtb + (vbase + q5) * TT + j0 + hi * 8;
    const u16* vp1 = vtb + (vbase + 32 + q5) * TT + j0 + hi * 8;
    s16x8 vfr0[4], vfr1[4];
#pragma unroll
    for (int c = 0; c < 4; ++c) {
      vfr0[c] = *(const s16x8*)(vp0 + c * 16);
      vfr1[c] = *(const s16x8*)(vp1 + c * 16);
    }
    // ---- bias (+ causal mask only on last tile) ----
    float dif0h = (float)(qrow - j0) - 4.0f * (float)hi;
    if (jt == nt - 1) {
#pragma unroll
      for (int r = 0; r < 16; ++r) {
        float cr = (float)((r & 3) + 8 * (r >> 2));
        float d0 = dif0h - cr, d1 = d0 - 32.f;
        float sv0 = s0[r] - d0 * cgA[r >> 2][r & 3];
        float sv1 = s1[r] - d1 * cgB[r >> 2][r & 3];
        s0[r] = (d0 >= 0.f) ? sv0 : -1e30f;
        s1[r] = (d1 >= 0.f) ? sv1 : -1e30f;
      }
    } else {
#pragma unroll
      for (int r = 0; r < 16; ++r) {
        float cr = (float)((r & 3) + 8 * (r >> 2));
        float d0 = dif0h - cr;
        s0[r] = s0[r] - d0 * cgA[r >> 2][r & 3];
        s1[r] = s1[r] - (d0 - 32.f) * cgB[r >> 2][r & 3];
      }
    }
    // ---- max tree + cross-half ----
    float t8[8];
#pragma unroll
    for (int i = 0; i < 8; ++i)
      t8[i] = fmaxf(fmaxf(s0[i], s0[i + 8]), fmaxf(s1[i], s1[i + 8]));
    float pmax = fmaxf(fmaxf(fmaxf(t8[0], t8[4]), fmaxf(t8[1], t8[5])),
                       fmaxf(fmaxf(t8[2], t8[6]), fmaxf(t8[3], t8[7])));
    pmax = fmaxf(pmax, __shfl_xor(pmax, 32, 64));
    // ---- defer-max: rescale only when max grew materially (THR = 8*log2e) ----
    if (!__all(pmax - m <= 11.54f)) {
      float mn = fmaxf(m, pmax);
      float al = exp2f(m - mn);
      m = mn;
      l *= al;
#pragma unroll
      for (int r = 0; r < 16; ++r) { accO[0][r] *= al; accO[1][r] *= al; }
    }
    // ---- exp2 + sum tree ----
#pragma unroll
    for (int r = 0; r < 16; ++r) {
      s0[r] = exp2f(s0[r] - m);
      s1[r] = exp2f(s1[r] - m);
    }
    float e8[8];
#pragma unroll
    for (int i = 0; i < 8; ++i)
      e8[i] = (s0[i] + s0[i + 8]) + (s1[i] + s1[i + 8]);
    float ps = ((e8[0] + e8[4]) + (e8[1] + e8[5])) + ((e8[2] + e8[6]) + (e8[3] + e8[7]));
    ps += __shfl_xor(ps, 32, 64);
    l += ps;
    // ---- P^T -> bf16 B-frags (permlane32_swap) + PV: O^T += V^T P^T ----
    auto pvchunk = [&](const f32x16& sc, const s16x8& v00, const s16x8& v01,
                       const s16x8& v10, const s16x8& v11) {
      u32 c01 = pk2(sc[0], sc[1]),  c23 = pk2(sc[2], sc[3]);
      u32 c45 = pk2(sc[4], sc[5]),  c67 = pk2(sc[6], sc[7]);
      u32 c89 = pk2(sc[8], sc[9]),  cAB = pk2(sc[10], sc[11]);
      u32 cCD = pk2(sc[12], sc[13]), cEF = pk2(sc[14], sc[15]);
      union { u32 wd[4]; s16x8 v; } Bf0, Bf1;
#if __has_builtin(__builtin_amdgcn_permlane32_swap)
      u32x2 sA = __builtin_amdgcn_permlane32_swap(c01, c45, false, false);
      u32x2 sB = __builtin_amdgcn_permlane32_swap(c23, c67, false, false);
      u32x2 sC = __builtin_amdgcn_permlane32_swap(c89, cCD, false, false);
      u32x2 sD = __builtin_amdgcn_permlane32_swap(cAB, cEF, false, false);
      Bf0.wd[0] = sA.x; Bf0.wd[1] = sB.x; Bf0.wd[2] = sA.y; Bf0.wd[3] = sB.y;
      Bf1.wd[0] = sC.x; Bf1.wd[1] = sD.x; Bf1.wd[2] = sC.y; Bf1.wd[3] = sD.y;
#else
      u32 x01 = (u32)__shfl_xor((int)c01, 32, 64), x23 = (u32)__shfl_xor((int)c23, 32, 64);
      u32 x45 = (u32)__shfl_xor((int)c45, 32, 64), x67 = (u32)__shfl_xor((int)c67, 32, 64);
      u32 x89 = (u32)__shfl_xor((int)c89, 32, 64), xAB = (u32)__shfl_xor((int)cAB, 32, 64);
      u32 xCD = (u32)__shfl_xor((int)cCD, 32, 64), xEF = (u32)__shfl_xor((int)cEF, 32, 64);
      Bf0.wd[0] = hi ? x45 : c01; Bf0.wd[1] = hi ? x67 : c23;
      Bf0.wd[2] = hi ? c45 : x01; Bf0.wd[3] = hi ? c67 : x23;
      Bf1.wd[0] = hi ? xCD : c89; Bf1.wd[1] = hi ? xEF : cAB;
      Bf1.wd[2] = hi ? cCD : x89; Bf1.wd[3] = hi ? cEF : xAB;
#endif
      accO[0] = __builtin_amdgcn_mfma_f32_32x32x16_bf16(v00, Bf0.v, accO[0], 0, 0, 0);
      accO[0] = __builtin_amdgcn_mfma_f32_32x32x16_bf16(v01, Bf1.v, accO[0], 0, 0, 0);
      accO[1] = __builtin_amdgcn_mfma_f32_32x32x16_bf16(v10, Bf0.v, accO[1], 0, 0, 0);
      accO[1] = __builtin_amdgcn_mfma_f32_32x32x16_bf16(v11, Bf1.v, accO[1], 0, 0, 0);
    };
    pvchunk(s0, vfr0[0], vfr0[1], vfr1[0], vfr1[1]);
    pvchunk(s1, vfr0[2], vfr0[3], vfr1[2], vfr1[3]);
  }
  // ---- merge the two KV-splits via LDS ----
  if (w == 1) {
#pragma unroll
    for (int r = 0; r < 16; ++r) {
      mO[r][lane] = accO[0][r];
      mO[16 + r][lane] = accO[1][r];
    }
    mML[0][lane] = m;
    mML[1][lane] = l;
  }
  __syncthreads();
  if (w == 1) return;
  float m1 = mML[0][lane], l1 = mML[1][lane];
  float ms = fmaxf(m, m1);
  float a0 = exp2f(m - ms), a1 = exp2f(m1 - ms);
  float lt = l * a0 + l1 * a1;
  float inv0 = a0 / lt, inv1 = a1 / lt;
  // ---- epilogue: merged O^T -> LDS transpose -> coalesced bf16 stores (wave0) ----
#pragma unroll
  for (int dt = 0; dt < 2; ++dt)
#pragma unroll
    for (int r = 0; r < 16; ++r) {
      float val = accO[dt][r] * inv0 + mO[dt * 16 + r][lane] * inv1;
      int d = 32 * dt + (r & 3) + 8 * (r >> 2) + 4 * hi;
      *(u16*)((char*)ol + q5 * 128 + (((d >> 3) ^ SWZ(q5)) << 4) + ((d & 7) << 1)) = f2b(val);
    }
  int row = lane >> 1, half = lane & 1;
#pragma unroll
  for (int s4 = 0; s4 < 4; ++s4) {
    int slot = half * 4 + s4;
    s16x8 vv = *(const s16x8*)((char*)ol + row * 128 + ((slot ^ SWZ(row)) << 4));
    *(s16x8*)(y + ((size_t)(b * TT) + qt * 32 + row) * CE + h * HD + half * 32 + s4 * 8) = vv;
  }
}

extern "C" void kernel_launch(void* const* d_in, const int* in_sizes, int n_in,
                              void* d_out, int out_size, void* d_ws, size_t ws_size,
                              hipStream_t stream) {
  const float* x  = (const float*)d_in[0];
  const float* Wq = (const float*)d_in[1];
  const float* Wk = (const float*)d_in[2];
  const float* Wv = (const float*)d_in[3];
  const float* Wp = (const float*)d_in[4];
  const float* qw = (const float*)d_in[5];
  const float* kw = (const float*)d_in[6];
  const float* om = (const float*)d_in[7];
  const float* u  = (const float*)d_in[8];
  float* out = (float*)d_out;
  char* ws = (char*)d_ws;
  const size_t MB = 1024 * 1024;
  u16* xb  = (u16*)(ws + 0);
  u16* wqt = (u16*)(ws + 8 * MB);
  u16* wkt = (u16*)(ws + 10 * MB);
  u16* wvt = (u16*)(ws + 12 * MB);
  u16* wpt = (u16*)(ws + 14 * MB);
  float* qf = (float*)(ws + 16 * MB);
  float* kf = (float*)(ws + 32 * MB);
  float* vf = (float*)(ws + 48 * MB);
  u16* qbb = (u16*)(ws + 64 * MB);
  u16* kbb = (u16*)(ws + 72 * MB);
  u16* vtb = (u16*)(ws + 80 * MB);
  float* cg = (float*)(ws + 88 * MB);
  u16* yb = (u16*)(ws + 16 * MB);   // reuse qf region

  cvt_x<<<dim3(2048), dim3(256), 0, stream>>>(x, xb, MR * CE / 4);
  cvt_wt<<<dim3(16, 16, 4), dim3(256), 0, stream>>>(Wq, Wk, Wv, Wp, wqt, wkt, wvt, wpt);
  gemm3<<<dim3(8, 32, 3), dim3(256), 0, stream>>>(xb, wqt, wkt, wvt, qf, kf, vf, MR, CE, CE);
  rmsgate<<<dim3(32, 16, 2), dim3(256), 0, stream>>>(qf, kf, vf, qw, kw, om, u, qbb, kbb, vtb, cg);
  attn<<<dim3(64, 16, 2), dim3(128), 0, stream>>>(qbb, kbb, vtb, cg, yb);
  gemm3<<<dim3(8, 32, 1), dim3(256), 0, stream>>>(yb, wpt, wpt, wpt, out, out, out, MR, CE, CE);
}

// Round 9
// 313.489 us; speedup vs baseline: 1.6265x; 1.0231x over previous
//
#include <hip/hip_runtime.h>
#include <hip/hip_bf16.h>

#define NH 16
#define HD 64
#define CE 1024
#define TT 2048
#define BB 2
#define MR (BB*TT)   // 4096 rows
#define SWZ(r) ((((r) & 7)) ^ (((r) >> 3) & 3))
#define LOG2E 1.44269504f

typedef __attribute__((ext_vector_type(4))) float f32x4;
typedef __attribute__((ext_vector_type(16))) float f32x16;
typedef __attribute__((ext_vector_type(8))) short s16x8;
typedef __attribute__((ext_vector_type(2))) unsigned int u32x2;
typedef unsigned int u32;
typedef unsigned short u16;

__device__ __forceinline__ void gld16(const void* g, void* l) {
  __builtin_amdgcn_global_load_lds((const __attribute__((address_space(1))) unsigned int*)g,
                                   (__attribute__((address_space(3))) unsigned int*)l, 16, 0, 0);
}
__device__ __forceinline__ u16 f2b(float f) {
  union { __hip_bfloat16 b; u16 u; } t;
  t.b = __float2bfloat16(f);
  return t.u;
}
__device__ __forceinline__ u32 pk2(float a, float b) {
  return (u32)f2b(a) | ((u32)f2b(b) << 16);
}
__device__ __forceinline__ float red64_sum(float v) {
#pragma unroll
  for (int m = 1; m < 64; m <<= 1) v += __shfl_xor(v, m, 64);
  return v;
}
__device__ __forceinline__ float softplusf(float x) {
  return x > 20.0f ? x : log1pf(expf(x));
}

// ---------------- x -> bf16 ----------------
__global__ __launch_bounds__(256) void cvt_x(const float* __restrict__ x,
                                             u16* __restrict__ xb, int n4) {
  int stride = gridDim.x * blockDim.x;
  for (int i = blockIdx.x * blockDim.x + threadIdx.x; i < n4; i += stride) {
    float4 v = ((const float4*)x)[i];
    union { u16 u[4]; uint2 p; } o;
    o.u[0] = f2b(v.x); o.u[1] = f2b(v.y); o.u[2] = f2b(v.z); o.u[3] = f2b(v.w);
    ((uint2*)xb)[i] = o.p;
  }
}

// ------- W [K][N] fp32 -> Wt [N][K] bf16 -------
__global__ __launch_bounds__(256) void cvt_wt(const float* __restrict__ W0, const float* __restrict__ W1,
                                              const float* __restrict__ W2, const float* __restrict__ W3,
                                              u16* __restrict__ T0, u16* __restrict__ T1,
                                              u16* __restrict__ T2, u16* __restrict__ T3) {
  const float* W = blockIdx.z == 0 ? W0 : blockIdx.z == 1 ? W1 : blockIdx.z == 2 ? W2 : W3;
  u16* T = blockIdx.z == 0 ? T0 : blockIdx.z == 1 ? T1 : blockIdx.z == 2 ? T2 : T3;
  __shared__ float t[64][65];
  int k0 = blockIdx.x * 64, n0 = blockIdx.y * 64;
  int row = threadIdx.x >> 2, seg = threadIdx.x & 3;
#pragma unroll
  for (int i = 0; i < 4; ++i) {
    float4 v = *(const float4*)(W + (size_t)(k0 + row) * CE + n0 + seg * 16 + i * 4);
    int c = seg * 16 + i * 4;
    t[row][c + 0] = v.x; t[row][c + 1] = v.y; t[row][c + 2] = v.z; t[row][c + 3] = v.w;
  }
  __syncthreads();
#pragma unroll
  for (int it = 0; it < 2; ++it) {
    int c = threadIdx.x + it * 256;
    int n = c >> 3, ks = (c & 7) * 8;
    union { u16 u[8]; uint4 p; } o;
#pragma unroll
    for (int e = 0; e < 8; ++e) o.u[e] = f2b(t[ks + e][n]);
    *(uint4*)(T + (size_t)(n0 + n) * CE + k0 + ks) = o.p;
  }
}

// ---------------- bf16 GEMM: C[M,N] = A[M,K] @ Bt[N,K]^T ----------------
#define BM 128
#define BN 128
#define BK 64
__global__ __launch_bounds__(256) void gemm3(const u16* __restrict__ A,
    const u16* __restrict__ B0, const u16* __restrict__ B1,
    const u16* __restrict__ B2,
    float* __restrict__ C0, float* __restrict__ C1, float* __restrict__ C2,
    int M, int N, int K) {
  const u16* Bt = blockIdx.z == 0 ? B0 : blockIdx.z == 1 ? B1 : B2;
  float* C = blockIdx.z == 0 ? C0 : blockIdx.z == 1 ? C1 : C2;
  __shared__ __align__(16) u16 aT[BM * BK];  // linear dest; source pre-swizzled
  __shared__ __align__(16) u16 bT[BN * BK];
  int tid = threadIdx.x;
  int w = tid >> 6, lane = tid & 63, q4 = lane >> 4, r16 = lane & 15;
  int m0 = blockIdx.y * BM, n0 = blockIdx.x * BN;
  int wm = (w >> 1) * 64, wn = (w & 1) * 64;
  f32x4 acc[4][4] = {};
  for (int k0 = 0; k0 < K; k0 += BK) {
#pragma unroll
    for (int it = 0; it < 4; ++it) {
      int c = tid + it * 256;
      int row = c >> 3, sl = c & 7;
      gld16(A + (size_t)(m0 + row) * K + k0 + ((sl ^ SWZ(row)) << 3), &aT[c * 8]);
      gld16(Bt + (size_t)(n0 + row) * K + k0 + ((sl ^ SWZ(row)) << 3), &bT[c * 8]);
    }
    __syncthreads();
#pragma unroll
    for (int kk = 0; kk < 2; ++kk) {
      s16x8 af[4], bfr[4];
#pragma unroll
      for (int i = 0; i < 4; ++i) {
        int ra = wm + i * 16 + r16;
        af[i] = *(const s16x8*)((char*)aT + ra * 128 + ((((kk << 2) | q4) ^ SWZ(ra)) << 4));
        int rb = wn + i * 16 + r16;
        bfr[i] = *(const s16x8*)((char*)bT + rb * 128 + ((((kk << 2) | q4) ^ SWZ(rb)) << 4));
      }
#pragma unroll
      for (int i = 0; i < 4; ++i)
#pragma unroll
        for (int j = 0; j < 4; ++j)
          acc[i][j] = __builtin_amdgcn_mfma_f32_16x16x32_bf16(af[i], bfr[j], acc[i][j], 0, 0, 0);
    }
    __syncthreads();
  }
#pragma unroll
  for (int i = 0; i < 4; ++i)
#pragma unroll
    for (int j = 0; j < 4; ++j)
#pragma unroll
      for (int r = 0; r < 4; ++r) {
        int gm = m0 + wm + i * 16 + (q4 << 2) + r;
        int gn = n0 + wn + j * 16 + r16;
        C[(size_t)gm * N + gn] = acc[i][j][r];
      }
}

// ---- RMSNorm(q,k) + gate; q -> [B,H,T,D] bf16 (scale*log2e folded in),
//      k -> [B,H,D/8,T,8] bf16 (coalesced MFMA A-frag loads in attn),
//      v -> [B,H,T/8,D,8] bf16 (coalesced PV A-frag loads),
//      cg pre-multiplied by log2e ----
__global__ __launch_bounds__(256) void rmsgate(const float* __restrict__ q, const float* __restrict__ k,
    const float* __restrict__ v, const float* __restrict__ qw, const float* __restrict__ kw,
    const float* __restrict__ omega, const float* __restrict__ u,
    u16* __restrict__ qb, u16* __restrict__ kb,
    u16* __restrict__ vtb, float* __restrict__ cg) {
  int b = blockIdx.z, h = blockIdx.y, t0 = blockIdx.x * 64;
  int tid = threadIdx.x, w = tid >> 6, lane = tid & 63;
  float uv = u[h * HD + lane];
  float us = red64_sum(uv * uv);
  float un = uv / fmaxf(sqrtf(us), 1e-6f);
  float qwl = qw[lane], kwl = kw[lane];
  float weff = softplusf(omega[h]) * exp2f(-0.5f * (float)(h + 1)) * LOG2E;
  int bh = b * NH + h;
  size_t hb = (size_t)bh * TT;
  u16* kb8 = kb + ((size_t)bh * 8 + (lane >> 3)) * (TT * 8) + (lane & 7);
#pragma unroll 4
  for (int it = 0; it < 16; ++it) {
    int t = t0 + w * 16 + it;
    size_t roff = ((size_t)(b * TT + t)) * CE + h * HD + lane;
    float qv = q[roff];
    float rq = rsqrtf(red64_sum(qv * qv) * (1.0f / 64.0f) + 1e-5f);
    qb[(hb + t) * HD + lane] = f2b(qv * rq * qwl * (0.125f * LOG2E));
    float kv = k[roff];
    float rk = rsqrtf(red64_sum(kv * kv) * (1.0f / 64.0f) + 1e-5f);
    float kn = kv * rk * kwl;
    kb8[t * 8] = f2b(kn);
    float gl = red64_sum(kn * un) * 0.125f;
    if (lane == 0) cg[hb + t] = weff * softplusf(gl);
  }
  __shared__ u16 vt[64 * 65];
  int row = tid >> 2, seg = tid & 3;
#pragma unroll
  for (int i = 0; i < 4; ++i) {
    float4 vv = *(const float4*)(v + ((size_t)(b * TT + t0 + row)) * CE + h * HD + seg * 16 + i * 4);
    int d = seg * 16 + i * 4;
    vt[(d + 0) * 65 + row] = f2b(vv.x);
    vt[(d + 1) * 65 + row] = f2b(vv.y);
    vt[(d + 2) * 65 + row] = f2b(vv.z);
    vt[(d + 3) * 65 + row] = f2b(vv.w);
  }
  __syncthreads();
#pragma unroll
  for (int it = 0; it < 2; ++it) {
    int c = tid + it * 256;
    int d = c & 63, jc = c >> 6;   // jc 0..7 across both iterations
    union { u16 u[8]; uint4 p; } o;
#pragma unroll
    for (int e = 0; e < 8; ++e) o.u[e] = vt[d * 65 + jc * 8 + e];
    *(uint4*)(vtb + (((size_t)bh * 256 + (t0 >> 3) + jc) * 64 + d) * 8) = o.p;
  }
}

// ------------- causal flash attention: split-KV x2, 2 waves/block -------------
// K [B,H,D/8,T,8] and V [B,H,T/8,D,8] layouts make every fragment load two
// 512B-contiguous lane-group segments (8 lines/instr vs 32 before).
#define KVB 64
__global__ __launch_bounds__(128) void attn(const u16* __restrict__ qb,
    const u16* __restrict__ kb, const u16* __restrict__ vtb,
    const float* __restrict__ cg, u16* __restrict__ y) {
  int b = blockIdx.z, h = blockIdx.y;
  int qt = gridDim.x - 1 - blockIdx.x;          // heavy tiles dispatch first
  int tid = threadIdx.x;
  int w = tid >> 6;                             // KV-split index (0/1)
  int lane = tid & 63;
  int hi = lane >> 5, q5 = lane & 31;
  __shared__ __align__(16) u16 ol[32 * 64];     // 4KB epilogue transpose
  __shared__ float mO[32][64];                  // 8KB wave1 accO
  __shared__ float mML[2][64];                  // wave1 m,l
  int bh = b * NH + h;
  size_t hb = (size_t)bh * TT;
  const u16* kbase = kb + (size_t)bh * 8 * (TT * 8);     // [8][T][8]
  const u16* vbase = vtb + (size_t)bh * 256 * (64 * 8);  // [256][64][8]
  int qrow = qt * 32 + q5;
  const u16* qptr = qb + (hb + qrow) * HD;
  s16x8 qf[4];
#pragma unroll
  for (int kc = 0; kc < 4; ++kc)
    qf[kc] = *(const s16x8*)(qptr + kc * 16 + hi * 8);
  f32x16 accO[2] = {};   // O^T tiles (d 0..31 / 32..63) x q
  float m = -1e30f, l = 0.f;
  int nt = qt / 2 + 1;
  for (int jt = w; jt < nt; jt += 2) {
    int j0 = jt * KVB;
    // ---- K + cg loads (K: lanes 0-31 / 32-63 each 512B contiguous) ----
    const u16* kp = kbase + ((size_t)hi * TT + j0 + q5) * 8;
    s16x8 kf0[4], kf1[4];
#pragma unroll
    for (int kc = 0; kc < 4; ++kc) {
      kf0[kc] = *(const s16x8*)(kp + kc * (2 * TT * 8));
      kf1[kc] = *(const s16x8*)(kp + kc * (2 * TT * 8) + 256);
    }
    const float* cgp = cg + hb + j0 + 4 * hi;
    f32x4 cgA[4], cgB[4];
#pragma unroll
    for (int g = 0; g < 4; ++g) {
      cgA[g] = *(const f32x4*)(cgp + 8 * g);
      cgB[g] = *(const f32x4*)(cgp + 32 + 8 * g);
    }
    // ---- S^T = K Q ----
    f32x16 s0 = {}, s1 = {};
#pragma unroll
    for (int kc = 0; kc < 4; ++kc) {
      s0 = __builtin_amdgcn_mfma_f32_32x32x16_bf16(kf0[kc], qf[kc], s0, 0, 0, 0);
      s1 = __builtin_amdgcn_mfma_f32_32x32x16_bf16(kf1[kc], qf[kc], s1, 0, 0, 0);
    }
    // ---- issue V loads now (K regs dead; latency hides under softmax) ----
    const u16* vp = vbase + (((size_t)(j0 >> 3) + hi) * 64 + q5) * 8;
    s16x8 vfr0[4], vfr1[4];
#pragma unroll
    for (int c = 0; c < 4; ++c) {
      vfr0[c] = *(const s16x8*)(vp + c * 1024);        // d = q5
      vfr1[c] = *(const s16x8*)(vp + c * 1024 + 256);  // d = q5 + 32
    }
    // ---- bias (+ causal mask only on last tile) ----
    float dif0h = (float)(qrow - j0) - 4.0f * (float)hi;
    if (jt == nt - 1) {
#pragma unroll
      for (int r = 0; r < 16; ++r) {
        float cr = (float)((r & 3) + 8 * (r >> 2));
        float d0 = dif0h - cr, d1 = d0 - 32.f;
        float sv0 = s0[r] - d0 * cgA[r >> 2][r & 3];
        float sv1 = s1[r] - d1 * cgB[r >> 2][r & 3];
        s0[r] = (d0 >= 0.f) ? sv0 : -1e30f;
        s1[r] = (d1 >= 0.f) ? sv1 : -1e30f;
      }
    } else {
#pragma unroll
      for (int r = 0; r < 16; ++r) {
        float cr = (float)((r & 3) + 8 * (r >> 2));
        float d0 = dif0h - cr;
        s0[r] = s0[r] - d0 * cgA[r >> 2][r & 3];
        s1[r] = s1[r] - (d0 - 32.f) * cgB[r >> 2][r & 3];
      }
    }
    // ---- max tree + cross-half ----
    float t8[8];
#pragma unroll
    for (int i = 0; i < 8; ++i)
      t8[i] = fmaxf(fmaxf(s0[i], s0[i + 8]), fmaxf(s1[i], s1[i + 8]));
    float pmax = fmaxf(fmaxf(fmaxf(t8[0], t8[4]), fmaxf(t8[1], t8[5])),
                       fmaxf(fmaxf(t8[2], t8[6]), fmaxf(t8[3], t8[7])));
    pmax = fmaxf(pmax, __shfl_xor(pmax, 32, 64));
    // ---- defer-max: rescale only when max grew materially (THR = 8*log2e) ----
    if (!__all(pmax - m <= 11.54f)) {
      float mn = fmaxf(m, pmax);
      float al = exp2f(m - mn);
      m = mn;
      l *= al;
#pragma unroll
      for (int r = 0; r < 16; ++r) { accO[0][r] *= al; accO[1][r] *= al; }
    }
    // ---- exp2 + sum tree ----
#pragma unroll
    for (int r = 0; r < 16; ++r) {
      s0[r] = exp2f(s0[r] - m);
      s1[r] = exp2f(s1[r] - m);
    }
    float e8[8];
#pragma unroll
    for (int i = 0; i < 8; ++i)
      e8[i] = (s0[i] + s0[i + 8]) + (s1[i] + s1[i + 8]);
    float ps = ((e8[0] + e8[4]) + (e8[1] + e8[5])) + ((e8[2] + e8[6]) + (e8[3] + e8[7]));
    ps += __shfl_xor(ps, 32, 64);
    l += ps;
    // ---- P^T -> bf16 B-frags (permlane32_swap) + PV: O^T += V^T P^T ----
    auto pvchunk = [&](const f32x16& sc, const s16x8& v00, const s16x8& v01,
                       const s16x8& v10, const s16x8& v11) {
      u32 c01 = pk2(sc[0], sc[1]),  c23 = pk2(sc[2], sc[3]);
      u32 c45 = pk2(sc[4], sc[5]),  c67 = pk2(sc[6], sc[7]);
      u32 c89 = pk2(sc[8], sc[9]),  cAB = pk2(sc[10], sc[11]);
      u32 cCD = pk2(sc[12], sc[13]), cEF = pk2(sc[14], sc[15]);
      union { u32 wd[4]; s16x8 v; } Bf0, Bf1;
#if __has_builtin(__builtin_amdgcn_permlane32_swap)
      u32x2 sA = __builtin_amdgcn_permlane32_swap(c01, c45, false, false);
      u32x2 sB = __builtin_amdgcn_permlane32_swap(c23, c67, false, false);
      u32x2 sC = __builtin_amdgcn_permlane32_swap(c89, cCD, false, false);
      u32x2 sD = __builtin_amdgcn_permlane32_swap(cAB, cEF, false, false);
      Bf0.wd[0] = sA.x; Bf0.wd[1] = sB.x; Bf0.wd[2] = sA.y; Bf0.wd[3] = sB.y;
      Bf1.wd[0] = sC.x; Bf1.wd[1] = sD.x; Bf1.wd[2] = sC.y; Bf1.wd[3] = sD.y;
#else
      u32 x01 = (u32)__shfl_xor((int)c01, 32, 64), x23 = (u32)__shfl_xor((int)c23, 32, 64);
      u32 x45 = (u32)__shfl_xor((int)c45, 32, 64), x67 = (u32)__shfl_xor((int)c67, 32, 64);
      u32 x89 = (u32)__shfl_xor((int)c89, 32, 64), xAB = (u32)__shfl_xor((int)cAB, 32, 64);
      u32 xCD = (u32)__shfl_xor((int)cCD, 32, 64), xEF = (u32)__shfl_xor((int)cEF, 32, 64);
      Bf0.wd[0] = hi ? x45 : c01; Bf0.wd[1] = hi ? x67 : c23;
      Bf0.wd[2] = hi ? c45 : x01; Bf0.wd[3] = hi ? c67 : x23;
      Bf1.wd[0] = hi ? xCD : c89; Bf1.wd[1] = hi ? xEF : cAB;
      Bf1.wd[2] = hi ? cCD : x89; Bf1.wd[3] = hi ? cEF : xAB;
#endif
      accO[0] = __builtin_amdgcn_mfma_f32_32x32x16_bf16(v00, Bf0.v, accO[0], 0, 0, 0);
      accO[0] = __builtin_amdgcn_mfma_f32_32x32x16_bf16(v01, Bf1.v, accO[0], 0, 0, 0);
      accO[1] = __builtin_amdgcn_mfma_f32_32x32x16_bf16(v10, Bf0.v, accO[1], 0, 0, 0);
      accO[1] = __builtin_amdgcn_mfma_f32_32x32x16_bf16(v11, Bf1.v, accO[1], 0, 0, 0);
    };
    pvchunk(s0, vfr0[0], vfr0[1], vfr1[0], vfr1[1]);
    pvchunk(s1, vfr0[2], vfr0[3], vfr1[2], vfr1[3]);
  }
  // ---- merge the two KV-splits via LDS ----
  if (w == 1) {
#pragma unroll
    for (int r = 0; r < 16; ++r) {
      mO[r][lane] = accO[0][r];
      mO[16 + r][lane] = accO[1][r];
    }
    mML[0][lane] = m;
    mML[1][lane] = l;
  }
  __syncthreads();
  if (w == 1) return;
  float m1 = mML[0][lane], l1 = mML[1][lane];
  float ms = fmaxf(m, m1);
  float a0 = exp2f(m - ms), a1 = exp2f(m1 - ms);
  float lt = l * a0 + l1 * a1;
  float inv0 = a0 / lt, inv1 = a1 / lt;
  // ---- epilogue: merged O^T -> LDS transpose -> coalesced bf16 stores (wave0) ----
#pragma unroll
  for (int dt = 0; dt < 2; ++dt)
#pragma unroll
    for (int r = 0; r < 16; ++r) {
      float val = accO[dt][r] * inv0 + mO[dt * 16 + r][lane] * inv1;
      int d = 32 * dt + (r & 3) + 8 * (r >> 2) + 4 * hi;
      *(u16*)((char*)ol + q5 * 128 + (((d >> 3) ^ SWZ(q5)) << 4) + ((d & 7) << 1)) = f2b(val);
    }
  int row = lane >> 1, half = lane & 1;
#pragma unroll
  for (int s4 = 0; s4 < 4; ++s4) {
    int slot = half * 4 + s4;
    s16x8 vv = *(const s16x8*)((char*)ol + row * 128 + ((slot ^ SWZ(row)) << 4));
    *(s16x8*)(y + ((size_t)(b * TT) + qt * 32 + row) * CE + h * HD + half * 32 + s4 * 8) = vv;
  }
}

extern "C" void kernel_launch(void* const* d_in, const int* in_sizes, int n_in,
                              void* d_out, int out_size, void* d_ws, size_t ws_size,
                              hipStream_t stream) {
  const float* x  = (const float*)d_in[0];
  const float* Wq = (const float*)d_in[1];
  const float* Wk = (const float*)d_in[2];
  const float* Wv = (const float*)d_in[3];
  const float* Wp = (const float*)d_in[4];
  const float* qw = (const float*)d_in[5];
  const float* kw = (const float*)d_in[6];
  const float* om = (const float*)d_in[7];
  const float* u  = (const float*)d_in[8];
  float* out = (float*)d_out;
  char* ws = (char*)d_ws;
  const size_t MB = 1024 * 1024;
  u16* xb  = (u16*)(ws + 0);
  u16* wqt = (u16*)(ws + 8 * MB);
  u16* wkt = (u16*)(ws + 10 * MB);
  u16* wvt = (u16*)(ws + 12 * MB);
  u16* wpt = (u16*)(ws + 14 * MB);
  float* qf = (float*)(ws + 16 * MB);
  float* kf = (float*)(ws + 32 * MB);
  float* vf = (float*)(ws + 48 * MB);
  u16* qbb = (u16*)(ws + 64 * MB);
  u16* kbb = (u16*)(ws + 72 * MB);
  u16* vtb = (u16*)(ws + 80 * MB);
  float* cg = (float*)(ws + 88 * MB);
  u16* yb = (u16*)(ws + 16 * MB);   // reuse qf region

  cvt_x<<<dim3(2048), dim3(256), 0, stream>>>(x, xb, MR * CE / 4);
  cvt_wt<<<dim3(16, 16, 4), dim3(256), 0, stream>>>(Wq, Wk, Wv, Wp, wqt, wkt, wvt, wpt);
  gemm3<<<dim3(8, 32, 3), dim3(256), 0, stream>>>(xb, wqt, wkt, wvt, qf, kf, vf, MR, CE, CE);
  rmsgate<<<dim3(32, 16, 2), dim3(256), 0, stream>>>(qf, kf, vf, qw, kw, om, u, qbb, kbb, vtb, cg);
  attn<<<dim3(64, 16, 2), dim3(128), 0, stream>>>(qbb, kbb, vtb, cg, yb);
  gemm3<<<dim3(8, 32, 1), dim3(256), 0, stream>>>(yb, wpt, wpt, wpt, out, out, out, MR, CE, CE);
}